// Round 1
// 450.044 us; speedup vs baseline: 1.0331x; 1.0331x over previous
//
#include <hip/hip_runtime.h>
#include <hip/hip_bf16.h>
#include <math.h>

#define N_TOK 2048
#define DIM   1024
#define FF    2048
#define NEXP  8
#define NSLOT (N_TOK * 2)

typedef __attribute__((ext_vector_type(8))) short short8;
typedef __attribute__((ext_vector_type(4))) float f32x4;
typedef _Float16 half_t;
typedef __attribute__((ext_vector_type(4))) _Float16 h16x4;

__device__ __forceinline__ unsigned short f2bf(float f) {
    unsigned int u = __float_as_uint(f);
    u += 0x7FFFu + ((u >> 16) & 1u);   // round-to-nearest-even
    return (unsigned short)(u >> 16);
}

// async global->LDS 16B: LDS dst is wave-uniform base + lane*16
#define GLOAD_LDS16(g, l) \
    __builtin_amdgcn_global_load_lds((const __attribute__((address_space(1))) unsigned int*)(g), \
                                     (__attribute__((address_space(3))) unsigned int*)(l), 16, 0, 0)

// ---------------- router ------------------------------------------------------
__global__ __launch_bounds__(256) void k_router(const float* __restrict__ x,
        const float* __restrict__ Wg, int* __restrict__ hdr,
        int* __restrict__ tok_e, float* __restrict__ tok_w) {
    int wave = threadIdx.x >> 6, lane = threadIdx.x & 63;
    int t = blockIdx.x * 4 + wave;
    float acc[NEXP];
#pragma unroll
    for (int e = 0; e < NEXP; ++e) acc[e] = 0.f;
    const float* xr = x + (size_t)t * DIM;
    for (int d = lane; d < DIM; d += 64) {
        float xv = xr[d];
        const float* wr = Wg + d * NEXP;
#pragma unroll
        for (int e = 0; e < NEXP; ++e) acc[e] += xv * wr[e];
    }
#pragma unroll
    for (int off = 32; off > 0; off >>= 1) {
#pragma unroll
        for (int e = 0; e < NEXP; ++e) acc[e] += __shfl_down(acc[e], off);
    }
    if (lane == 0) {
        int e0 = 0;
#pragma unroll
        for (int e = 1; e < NEXP; ++e) if (acc[e] > acc[e0]) e0 = e;
        int e1 = -1;
#pragma unroll
        for (int e = 0; e < NEXP; ++e) {
            if (e == e0) continue;
            if (e1 < 0 || acc[e] > acc[e1]) e1 = e;
        }
        float w0 = 1.f / (1.f + expf(acc[e1] - acc[e0]));
        tok_e[2 * t] = e0; tok_e[2 * t + 1] = e1;
        tok_w[2 * t] = w0; tok_w[2 * t + 1] = 1.f - w0;
        atomicAdd(&hdr[e0], 1);
        atomicAdd(&hdr[e1], 1);
    }
}

// ---------------- scan --------------------------------------------------------
__global__ void k_scan(int* hdr) {
    if (threadIdx.x == 0 && blockIdx.x == 0) {
        int s = 0;
        for (int e = 0; e < NEXP; ++e) {
            hdr[16 + e] = s;
            hdr[8 + e]  = s;
            s += hdr[e];
        }
        hdr[24] = s;
    }
}

// ---------------- assign: slots + gather x -> bf16 ----------------------------
__global__ __launch_bounds__(256) void k_assign(const float* __restrict__ x,
        int* __restrict__ hdr, const int* __restrict__ tok_e,
        int* __restrict__ tok_slot, unsigned short* __restrict__ xg) {
    __shared__ int sh[2];
    int t = blockIdx.x;
    if (threadIdx.x == 0) {
        int e0 = tok_e[2 * t], e1 = tok_e[2 * t + 1];
        int p0 = atomicAdd(&hdr[8 + e0], 1);
        int p1 = atomicAdd(&hdr[8 + e1], 1);
        tok_slot[2 * t] = p0; tok_slot[2 * t + 1] = p1;
        sh[0] = p0; sh[1] = p1;
    }
    __syncthreads();
    int s0 = sh[0], s1 = sh[1];
    const float4* xr = (const float4*)(x + (size_t)t * DIM);
    float4 v = xr[threadIdx.x];
    ushort4 b;
    b.x = f2bf(v.x); b.y = f2bf(v.y); b.z = f2bf(v.z); b.w = f2bf(v.w);
    ((ushort4*)(xg + (size_t)s0 * DIM))[threadIdx.x] = b;
    ((ushort4*)(xg + (size_t)s1 * DIM))[threadIdx.x] = b;
}

// ---------------- weight transpose + fp32->bf16 -------------------------------
// [nmat][R][C] fp32 -> [nmat][C][R] bf16.  grid (C/64, R/64, nmat), 256 thr.
// LDS 64x64 tile; reads coalesced float4, writes coalesced 16B bf16.
__global__ __launch_bounds__(256) void k_cvt(const float* __restrict__ src,
        unsigned short* __restrict__ dst, int R, int C) {
    __shared__ unsigned short sh[64][65];   // +1 pad breaks bank conflicts
    const float* S = src + (size_t)blockIdx.z * R * C;
    unsigned short* Dp = dst + (size_t)blockIdx.z * R * C;
    int c0 = blockIdx.x * 64, r0 = blockIdx.y * 64;
    int t = threadIdx.x;
    int rr = t >> 2, c4 = (t & 3) * 4;      // 4 threads per row, 16 floats each
    const float* p = S + (size_t)(r0 + rr) * C + c0 + c4;
#pragma unroll
    for (int j = 0; j < 4; ++j) {
        float4 v = *(const float4*)(p + 16 * j);
        sh[rr][c4 + 16 * j + 0] = f2bf(v.x);
        sh[rr][c4 + 16 * j + 1] = f2bf(v.y);
        sh[rr][c4 + 16 * j + 2] = f2bf(v.z);
        sh[rr][c4 + 16 * j + 3] = f2bf(v.w);
    }
    __syncthreads();
    int oc = t >> 2, orr = (t & 3) * 16;    // 4 threads per out-row, 16 bf16 each
    unsigned short tmp[16];
#pragma unroll
    for (int j = 0; j < 16; ++j) tmp[j] = sh[orr + j][oc];
    unsigned short* q = Dp + (size_t)(c0 + oc) * R + r0 + orr;
    *(uint4*)q       = *(uint4*)&tmp[0];
    *(uint4*)(q + 8) = *(uint4*)&tmp[8];
}

// ---------------- expert dual-GEMM h & s + exact GELU -> inner (bf16) --------
// tile 128 x 64F, K-step 32, 4 waves 2x2.  A *and* B now staged via
// global_load_lds from bf16 K-contiguous buffers -> zero conversion VALU
// in the K-loop (m97 structure).
__global__ __launch_bounds__(256, 4) void k_expert_hs(
        const unsigned short* __restrict__ xg,
        const unsigned short* __restrict__ Wth,
        const unsigned short* __restrict__ Wts,
        const float* __restrict__ b_in, const float* __restrict__ b_sc,
        const int* __restrict__ hdr, unsigned short* __restrict__ inner) {
    int e = blockIdx.z;
    int cnt = hdr[e];
    int mtile = blockIdx.y;
    if (mtile * 128 >= cnt) return;
    int base = hdr[16 + e];
    int f0 = blockIdx.x * 64;

    __shared__ unsigned short As[128 * 32];  // [row][k] 64B rows
    __shared__ unsigned short Bh[64 * 32];   // [f][k]
    __shared__ unsigned short Bs[64 * 32];

    int tid = threadIdx.x;
    int wave = tid >> 6, lane = tid & 63;
    int lr = lane & 15, lq = lane >> 4;
    int wm = (wave >> 1) * 64, wf = (wave & 1) * 32;

    f32x4 acch[4][2], accs[4][2];
#pragma unroll
    for (int mi = 0; mi < 4; ++mi)
#pragma unroll
        for (int fi = 0; fi < 2; ++fi) {
            acch[mi][fi] = (f32x4){0.f, 0.f, 0.f, 0.f};
            accs[mi][fi] = (f32x4){0.f, 0.f, 0.f, 0.f};
        }

    int lrow = lane >> 2, lcol = (lane & 3) * 8;   // 4 lanes/row, 16B chunks
    const unsigned short* Ab = xg  + (size_t)(base + mtile * 128 + wave * 16 + lrow) * DIM + lcol;
    const unsigned short* Hb = Wth + ((size_t)e * FF + f0 + wave * 16 + lrow) * DIM + lcol;
    const unsigned short* Sb = Wts + ((size_t)e * FF + f0 + wave * 16 + lrow) * DIM + lcol;

    for (int k0 = 0; k0 < DIM; k0 += 32) {
        __syncthreads();   // prior frag reads done
        GLOAD_LDS16(Ab + k0, &As[(wave * 16) * 32]);
        GLOAD_LDS16(Ab + k0 + (size_t)64 * DIM, &As[(64 + wave * 16) * 32]);
        GLOAD_LDS16(Hb + k0, &Bh[(wave * 16) * 32]);
        GLOAD_LDS16(Sb + k0, &Bs[(wave * 16) * 32]);
        __syncthreads();   // implicit vmcnt(0) drain completes DMA

        short8 af[4], bhf[2], bsf[2];
#pragma unroll
        for (int mi = 0; mi < 4; ++mi)
            af[mi] = *(const short8*)&As[(wm + mi * 16 + lr) * 32 + lq * 8];
#pragma unroll
        for (int fi = 0; fi < 2; ++fi) {
            bhf[fi] = *(const short8*)&Bh[(wf + fi * 16 + lr) * 32 + lq * 8];
            bsf[fi] = *(const short8*)&Bs[(wf + fi * 16 + lr) * 32 + lq * 8];
        }
#pragma unroll
        for (int mi = 0; mi < 4; ++mi)
#pragma unroll
            for (int fi = 0; fi < 2; ++fi) {
                acch[mi][fi] = __builtin_amdgcn_mfma_f32_16x16x32_bf16(
                    af[mi], bhf[fi], acch[mi][fi], 0, 0, 0);
                accs[mi][fi] = __builtin_amdgcn_mfma_f32_16x16x32_bf16(
                    af[mi], bsf[fi], accs[mi][fi], 0, 0, 0);
            }
    }

#pragma unroll
    for (int fi = 0; fi < 2; ++fi) {
        int f = f0 + wf + fi * 16 + lr;
        float bi = b_in[e * FF + f];
        float bs2 = b_sc[e * FF + f];
#pragma unroll
        for (int mi = 0; mi < 4; ++mi) {
#pragma unroll
            for (int r = 0; r < 4; ++r) {
                int rl = wm + mi * 16 + lq * 4 + r;
                int grow = mtile * 128 + rl;
                if (grow < cnt) {
                    float h = acch[mi][fi][r] + bi;
                    float s = accs[mi][fi][r] + bs2;
                    float g = 0.5f * h * (1.f + erff(h * 0.70710678f));
                    inner[(size_t)(base + grow) * FF + f] = f2bf(g * s);
                }
            }
        }
    }
}

// ---------------- expert out-GEMM, split-K=2, fp16 partials -------------------
// tile 128 x 128D, 4 waves 2x2, A and B both via global_load_lds (bf16).
__global__ __launch_bounds__(256, 4) void k_expert_out(
        const unsigned short* __restrict__ inner,
        const unsigned short* __restrict__ Wto,
        const int* __restrict__ hdr, half_t* __restrict__ pbuf) {
    int e = blockIdx.z & 7;
    int ks = blockIdx.z >> 3;
    int cnt = hdr[e];
    int mtile = blockIdx.y;
    if (mtile * 128 >= cnt) return;
    int base = hdr[16 + e];
    int d0 = blockIdx.x * 128;

    __shared__ unsigned short As[128 * 32];  // [row][k]
    __shared__ unsigned short Bt[128 * 32];  // [d][k]

    int tid = threadIdx.x;
    int wave = tid >> 6, lane = tid & 63;
    int lr = lane & 15, lq = lane >> 4;
    int wm = (wave >> 1) * 64, wn = (wave & 1) * 64;

    f32x4 acc[4][4];
#pragma unroll
    for (int mi = 0; mi < 4; ++mi)
#pragma unroll
        for (int ni = 0; ni < 4; ++ni) acc[mi][ni] = (f32x4){0.f, 0.f, 0.f, 0.f};

    int lrow = lane >> 2, lcol = (lane & 3) * 8;
    const unsigned short* Ab = inner + (size_t)(base + mtile * 128 + wave * 16 + lrow) * FF + lcol;
    const unsigned short* Bb = Wto + ((size_t)e * DIM + d0 + wave * 16 + lrow) * FF + lcol;

    int kbeg = ks * (FF / 2), kend = kbeg + FF / 2;

    for (int k0 = kbeg; k0 < kend; k0 += 32) {
        __syncthreads();
        GLOAD_LDS16(Ab + k0, &As[(wave * 16) * 32]);
        GLOAD_LDS16(Ab + k0 + (size_t)64 * FF, &As[(64 + wave * 16) * 32]);
        GLOAD_LDS16(Bb + k0, &Bt[(wave * 16) * 32]);
        GLOAD_LDS16(Bb + k0 + (size_t)64 * FF, &Bt[(64 + wave * 16) * 32]);
        __syncthreads();

        short8 af[4], bfm[4];
#pragma unroll
        for (int mi = 0; mi < 4; ++mi)
            af[mi] = *(const short8*)&As[(wm + mi * 16 + lr) * 32 + lq * 8];
#pragma unroll
        for (int ni = 0; ni < 4; ++ni)
            bfm[ni] = *(const short8*)&Bt[(wn + ni * 16 + lr) * 32 + lq * 8];
#pragma unroll
        for (int mi = 0; mi < 4; ++mi)
#pragma unroll
            for (int ni = 0; ni < 4; ++ni)
                acc[mi][ni] = __builtin_amdgcn_mfma_f32_16x16x32_bf16(
                    af[mi], bfm[ni], acc[mi][ni], 0, 0, 0);
    }

    half_t* P = pbuf + (size_t)ks * NSLOT * DIM;
#pragma unroll
    for (int ni = 0; ni < 4; ++ni) {
        int d = d0 + wn + ni * 16 + lr;
#pragma unroll
        for (int mi = 0; mi < 4; ++mi) {
#pragma unroll
            for (int r = 0; r < 4; ++r) {
                int rl = wm + mi * 16 + lq * 4 + r;
                int grow = mtile * 128 + rl;
                if (grow < cnt)
                    P[(size_t)(base + grow) * DIM + d] = (half_t)acc[mi][ni][r];
            }
        }
    }
}

// ---------------- combine: out = w0*(p0+p1+b[e0]) + w1*(...) ------------------
__global__ __launch_bounds__(256) void k_combine(const half_t* __restrict__ pbuf,
        const int* __restrict__ tok_slot, const int* __restrict__ tok_e,
        const float* __restrict__ tok_w, const float* __restrict__ b_out,
        float* __restrict__ out) {
    int t = blockIdx.x;
    int d = threadIdx.x * 4;
    int s0 = tok_slot[2 * t], s1 = tok_slot[2 * t + 1];
    int e0 = tok_e[2 * t], e1 = tok_e[2 * t + 1];
    float w0 = tok_w[2 * t], w1 = tok_w[2 * t + 1];
    const half_t* pA = pbuf;
    const half_t* pB = pbuf + (size_t)NSLOT * DIM;
    h16x4 a0 = *(const h16x4*)&pA[(size_t)s0 * DIM + d];
    h16x4 a1 = *(const h16x4*)&pB[(size_t)s0 * DIM + d];
    h16x4 c0 = *(const h16x4*)&pA[(size_t)s1 * DIM + d];
    h16x4 c1 = *(const h16x4*)&pB[(size_t)s1 * DIM + d];
    float4 b0 = *(const float4*)&b_out[e0 * DIM + d];
    float4 b1 = *(const float4*)&b_out[e1 * DIM + d];
    float4 r;
    r.x = w0 * ((float)a0.x + (float)a1.x + b0.x) + w1 * ((float)c0.x + (float)c1.x + b1.x);
    r.y = w0 * ((float)a0.y + (float)a1.y + b0.y) + w1 * ((float)c0.y + (float)c1.y + b1.y);
    r.z = w0 * ((float)a0.z + (float)a1.z + b0.z) + w1 * ((float)c0.z + (float)c1.z + b1.z);
    r.w = w0 * ((float)a0.w + (float)a1.w + b0.w) + w1 * ((float)c0.w + (float)c1.w + b1.w);
    *(float4*)&out[(size_t)t * DIM + d] = r;
}

extern "C" void kernel_launch(void* const* d_in, const int* in_sizes, int n_in,
                              void* d_out, int out_size, void* d_ws, size_t ws_size,
                              hipStream_t stream) {
    (void)in_sizes; (void)n_in; (void)out_size; (void)ws_size;
    const float* x    = (const float*)d_in[0];
    const float* Wg   = (const float*)d_in[1];
    const float* Win  = (const float*)d_in[2];
    const float* b_in = (const float*)d_in[3];
    const float* Wsc  = (const float*)d_in[4];
    const float* b_sc = (const float*)d_in[5];
    const float* Wout = (const float*)d_in[6];
    const float* b_out= (const float*)d_in[7];
    float* out = (float*)d_out;

    // workspace layout (requires ~137 MB):
    //   hdr 256B | tok_e 16K | tok_w 16K | tok_slot 16K | pad
    //   xg 8M | inner 16M | pbuf 16M | wt_h 32M | wt_s 32M | wt_o 32M
    char* ws = (char*)d_ws;
    int*   hdr      = (int*)ws;
    int*   tok_e    = (int*)(ws + 256);
    float* tok_w    = (float*)(ws + 16640);
    int*   tok_slot = (int*)(ws + 33024);
    unsigned short* xg    = (unsigned short*)(ws + 65792);            // 8 MB
    unsigned short* inner = (unsigned short*)(ws + 65792 + 8388608);  // 16 MB
    half_t* pbuf = (half_t*)(ws + 65792 + 8388608 + 16777216);        // 16 MB
    unsigned short* wt_h = (unsigned short*)(ws + 65792 + 8388608 + 16777216 + 16777216);
    unsigned short* wt_s = wt_h + (size_t)NEXP * FF * DIM;            // +32 MB
    unsigned short* wt_o = wt_s + (size_t)NEXP * FF * DIM;            // +32 MB

    hipMemsetAsync(hdr, 0, 256, stream);
    // weight convert+transpose: [E][D][F] f32 -> [E][F][D] bf16 (W_in, W_scale)
    //                           [E][F][D] f32 -> [E][D][F] bf16 (W_out)
    k_cvt<<<dim3(FF / 64, DIM / 64, NEXP), dim3(256), 0, stream>>>(Win,  wt_h, DIM, FF);
    k_cvt<<<dim3(FF / 64, DIM / 64, NEXP), dim3(256), 0, stream>>>(Wsc,  wt_s, DIM, FF);
    k_cvt<<<dim3(DIM / 64, FF / 64, NEXP), dim3(256), 0, stream>>>(Wout, wt_o, FF, DIM);
    k_router<<<dim3(N_TOK / 4), dim3(256), 0, stream>>>(x, Wg, hdr, tok_e, tok_w);
    k_scan<<<dim3(1), dim3(64), 0, stream>>>(hdr);
    k_assign<<<dim3(N_TOK), dim3(256), 0, stream>>>(x, hdr, tok_e, tok_slot, xg);
    k_expert_hs<<<dim3(FF / 64, 16, NEXP), dim3(256), 0, stream>>>(xg, wt_h, wt_s, b_in, b_sc, hdr, inner);
    k_expert_out<<<dim3(DIM / 128, 16, NEXP * 2), dim3(256), 0, stream>>>(inner, wt_o, hdr, pbuf);
    k_combine<<<dim3(N_TOK), dim3(256), 0, stream>>>(pbuf, tok_slot, tok_e, tok_w, b_out, out);
}